// Round 5
// baseline (225.842 us; speedup 1.0000x reference)
//
#include <hip/hip_runtime.h>

typedef __attribute__((ext_vector_type(8)))  short short8;
typedef __attribute__((ext_vector_type(4)))  float f32x4;
typedef __attribute__((ext_vector_type(16))) float f32x16;

#define Bv 4
#define Sv 2048
#define Dv 1024
#define Hv 16
#define HDv 64

// workspace byte offsets
#define OFF_XB  (size_t)0           // X bf16      [8192][1024]  16MB
#define OFF_WC  (size_t)16777216    // Wcat bf16   [3072][1024]   6MB
#define OFF_M2  (size_t)23068672    // mask*log2e  [4][2048]     32KB
#define OFF_QB  (size_t)25165824    // Q bf16 [64][2048][64]     16MB (scaled 0.125*log2e)
#define OFF_KT  (size_t)41943040    // K tiled [64][32][8][1KB]  16MB
#define OFF_VT  (size_t)58720256    // V tiled [64][32][8][1KB]  16MB

#define QSCALE 0.180336879f   /* 0.125 * log2(e) */
#define LOG2E  1.44269504f

__device__ __forceinline__ unsigned short f2bf(float f) {
    union { float f; unsigned u; } v; v.f = f;
    unsigned r = v.u + 0x7FFFu + ((v.u >> 16) & 1u);   // RNE
    return (unsigned short)(r >> 16);
}
__device__ __forceinline__ float f4get(const float4& v, int i) {
    return i == 0 ? v.x : i == 1 ? v.y : i == 2 ? v.z : v.w;
}

#define GLOAD16(gp, lp)                                                        \
    __builtin_amdgcn_global_load_lds(                                          \
        (const __attribute__((address_space(1))) void*)(gp),                   \
        (__attribute__((address_space(3))) void*)(lp), 16, 0, 0)

// ---------------------------------------------------------------------------
// fp32 -> bf16 convert: X, Wq|Wk|Wv -> Wcat; mask -> mask*log2e (fp32)
// ---------------------------------------------------------------------------
__global__ void convert_kernel(const float* __restrict__ X,
                               const float* __restrict__ Wq,
                               const float* __restrict__ Wk,
                               const float* __restrict__ Wv,
                               const float* __restrict__ mask,
                               unsigned short* __restrict__ Xb,
                               unsigned short* __restrict__ Wc,
                               float* __restrict__ M2) {
    size_t i = ((size_t)blockIdx.x * 256 + threadIdx.x) * 4;
    if (i < 8388608) {
        float4 v = *(const float4*)(X + i);
        ushort4 o; o.x = f2bf(v.x); o.y = f2bf(v.y); o.z = f2bf(v.z); o.w = f2bf(v.w);
        *(ushort4*)(Xb + i) = o;
    } else if (i < 11534336) {
        size_t j = i - 8388608;
        int which = (int)(j >> 20);
        size_t r = j & 1048575;
        const float* W = which == 0 ? Wq : which == 1 ? Wk : Wv;
        float4 v = *(const float4*)(W + r);
        ushort4 o; o.x = f2bf(v.x); o.y = f2bf(v.y); o.z = f2bf(v.z); o.w = f2bf(v.w);
        *(ushort4*)(Wc + j) = o;
    } else {
        size_t j = i - 11534336;   // 8192 mask floats
        float4 v = *(const float4*)(mask + j);
        v.x *= LOG2E; v.y *= LOG2E; v.z *= LOG2E; v.w *= LOG2E;
        *(float4*)(M2 + j) = v;
    }
}

// ---------------------------------------------------------------------------
// QKV projection GEMM: [8192 x 1024] x [3072 x 1024]^T + bias -> bf16.
// Fragment-linear LDS staging, XCD-swizzled grid.
// Q row-major scaled by 0.125*log2e; K and V written in the attention
// kernel's fragment-chunk layout: [bh][kv_tile(32)][chunk(8)][1024B].
//   K chunk = ((s>>5)&1)*4 + (d>>4); byte = (s&31)*16 + ((d>>3)&1)*512 + (d&7)*2
//   V chunk = (d>>5)*4 + ((s>>4)&3); byte = (d&31)*16 + ((s>>3)&1)*512 + (s&7)*2
// ---------------------------------------------------------------------------
__global__ void qkv_gemm(const unsigned short* __restrict__ Xb,
                         const unsigned short* __restrict__ Wc,
                         const float* __restrict__ bq,
                         const float* __restrict__ bk,
                         const float* __restrict__ bv,
                         unsigned short* __restrict__ Qb,
                         char* __restrict__ Kt,
                         char* __restrict__ Vt) {
    __shared__ __align__(16) char sm[32768];
    char* As = sm;
    char* Bs = sm + 16384;

    const int tid  = threadIdx.x;
    const int w    = tid >> 6, lane = tid & 63;
    const int l15  = lane & 15, g = lane >> 4;

    const int lin  = blockIdx.x + (blockIdx.y << 6);
    const int lin2 = (lin & 7) * 192 + (lin >> 3);
    const int m0   = (lin2 / 24) * 128;
    const int n0   = (lin2 % 24) * 128;

    const int wr   = (w >> 1) * 64, wc = (w & 1) * 64;

    const size_t laneoff = (size_t)l15 * 2048 + g * 16;
    const char* gA0 = (const char*)Xb + ((size_t)m0 + 2 * w * 16) * 2048 + laneoff;
    const char* gB0 = (const char*)Wc + ((size_t)n0 + 2 * w * 16) * 2048 + laneoff;
    char* lA = As + (2 * w) * 2048;
    char* lB = Bs + (2 * w) * 2048;

    f32x4 acc[4][4];
#pragma unroll
    for (int a = 0; a < 4; ++a)
#pragma unroll
        for (int b = 0; b < 4; ++b)
#pragma unroll
            for (int r = 0; r < 4; ++r) acc[a][b][r] = 0.f;

    const int rbA = (w >> 1) * 4;
    const int rbB = (w & 1) * 4;

    for (int k0 = 0; k0 < 1024; k0 += 64) {
        __syncthreads();
#pragma unroll
        for (int i = 0; i < 2; ++i) {
#pragma unroll
            for (int ks = 0; ks < 2; ++ks) {
                GLOAD16(gA0 + i * 32768 + ks * 64 + k0 * 2, lA + i * 2048 + ks * 1024);
                GLOAD16(gB0 + i * 32768 + ks * 64 + k0 * 2, lB + i * 2048 + ks * 1024);
            }
        }
        __syncthreads();
#pragma unroll
        for (int ks = 0; ks < 2; ++ks) {
            short8 af[4], bf[4];
#pragma unroll
            for (int fm = 0; fm < 4; ++fm)
                af[fm] = *(const short8*)(As + ((rbA + fm) * 2 + ks) * 1024 + lane * 16);
#pragma unroll
            for (int fn = 0; fn < 4; ++fn)
                bf[fn] = *(const short8*)(Bs + ((rbB + fn) * 2 + ks) * 1024 + lane * 16);
#pragma unroll
            for (int fm = 0; fm < 4; ++fm)
#pragma unroll
                for (int fn = 0; fn < 4; ++fn)
                    acc[fm][fn] = __builtin_amdgcn_mfma_f32_16x16x32_bf16(
                        af[fm], bf[fn], acc[fm][fn], 0, 0, 0);
        }
    }

#pragma unroll
    for (int fn = 0; fn < 4; ++fn) {
        int ng = n0 + wc + fn * 16 + l15;
        int which = ng >> 10, nn = ng & 1023;
        const float* bias = which == 0 ? bq : which == 1 ? bk : bv;
        float bvv = bias[nn];
        int h = nn >> 6, d = nn & 63;
#pragma unroll
        for (int fm = 0; fm < 4; ++fm) {
            int m4 = m0 + wr + fm * 16 + 4 * g;
            int b = m4 >> 11, s4 = m4 & 2047;
            int bh = b * 16 + h;
            if (which == 0) {
#pragma unroll
                for (int r = 0; r < 4; ++r)
                    Qb[(size_t)(bh * 2048 + s4 + r) * 64 + d] =
                        f2bf((acc[fm][fn][r] + bvv) * QSCALE);
            } else if (which == 1) {
                char* base = Kt + ((size_t)bh * 32 + (s4 >> 6)) * 8192
                             + (((s4 >> 5) & 1) * 4 + (d >> 4)) * 1024
                             + ((d >> 3) & 1) * 512 + (d & 7) * 2
                             + (s4 & 31) * 16;
#pragma unroll
                for (int r = 0; r < 4; ++r)
                    *(unsigned short*)(base + r * 16) = f2bf(acc[fm][fn][r] + bvv);
            } else {
                char* base = Vt + ((size_t)bh * 32 + (s4 >> 6)) * 8192
                             + ((d >> 5) * 4 + ((s4 >> 4) & 3)) * 1024
                             + (d & 31) * 16 + ((s4 >> 3) & 1) * 512 + (s4 & 7) * 2;
                ushort4 pk;
                pk.x = f2bf(acc[fm][fn][0] + bvv);
                pk.y = f2bf(acc[fm][fn][1] + bvv);
                pk.z = f2bf(acc[fm][fn][2] + bvv);
                pk.w = f2bf(acc[fm][fn][3] + bvv);
                *(ushort4*)(base) = pk;
            }
        }
    }
}

// ---------------------------------------------------------------------------
// Flash attention: 4 waves x 64 q-rows, kv tiles of 64, triple-buffered
// fragment-linear LDS, counted-vmcnt pipeline (prefetch distance 2, raw
// barriers, never vmcnt(0) in the loop), mask in LDS, swapped S^T/O^T MFMA,
// exp2 softmax, cvt_pk+permlane packing, defer-max.
// ---------------------------------------------------------------------------
#define VM_WAIT4() do { asm volatile("s_waitcnt vmcnt(4)" ::: "memory"); \
                        __builtin_amdgcn_sched_barrier(0); } while (0)
#define BARRIER()  do { __builtin_amdgcn_s_barrier(); \
                        __builtin_amdgcn_sched_barrier(0); } while (0)

__global__ __launch_bounds__(256, 2) void attn_kernel(
    const unsigned short* __restrict__ Qg,
    const char* __restrict__ Kt,
    const char* __restrict__ Vt,
    const float* __restrict__ M2,
    float* __restrict__ out) {
    __shared__ __align__(16) char sm[57344];   // 3x16KB KV buffers + 8KB mask
    float* Msk = (float*)(sm + 49152);

    const int tid = threadIdx.x;
    const int w = tid >> 6, lane = tid & 63;
    const int l31 = lane & 31, g2 = lane >> 5;
    const int lin = blockIdx.x;
    const int bh = lin & 63, qt = lin >> 6;
    const int bb = bh >> 4, h = bh & 15;
    const int q0w = qt * 256 + w * 64;
    const float* mrow = M2 + bb * 2048;

    const char* KtB = Kt + (size_t)bh * 262144;   // 32 tiles * 8KB
    const char* VtB = Vt + (size_t)bh * 262144;
    const int c0 = 2 * w, c1 = 2 * w + 1;

    // mask -> LDS (8KB), 8 floats per thread
    {
        int idx = tid * 8;
        float4 a0 = *(const float4*)(mrow + idx);
        float4 a1 = *(const float4*)(mrow + idx + 4);
        *(float4*)(Msk + idx) = a0;
        *(float4*)(Msk + idx + 4) = a1;
    }

    // Q fragments (B-operand of S^T), already scaled by 0.125*log2e
    short8 qf[2][4];
#pragma unroll
    for (int qn = 0; qn < 2; ++qn)
#pragma unroll
        for (int ks = 0; ks < 4; ++ks)
            qf[qn][ks] = *(const short8*)(Qg + (size_t)(bh * 2048 + q0w + qn * 32 + l31) * 64
                                          + ks * 16 + g2 * 8);

    f32x16 o[2][2];
#pragma unroll
    for (int dm = 0; dm < 2; ++dm)
#pragma unroll
        for (int qn = 0; qn < 2; ++qn)
#pragma unroll
            for (int r = 0; r < 16; ++r) o[dm][qn][r] = 0.f;
    float mN[2] = {-3e38f, -3e38f}, lN[2] = {0.f, 0.f};

    __syncthreads();   // mask visible; drains all prologue vmem (exact counting after)

    // prologue: stage tiles 0,1 into slots 0,1 (4 gloads each)
#pragma unroll
    for (int p = 0; p < 2; ++p) {
        char* Kb = sm + p * 16384, *Vb = Kb + 8192;
        const char* kc = KtB + (size_t)p * 8192 + lane * 16;
        const char* vc = VtB + (size_t)p * 8192 + lane * 16;
        GLOAD16(kc + c0 * 1024, Kb + c0 * 1024);
        GLOAD16(kc + c1 * 1024, Kb + c1 * 1024);
        GLOAD16(vc + c0 * 1024, Vb + c0 * 1024);
        GLOAD16(vc + c1 * 1024, Vb + c1 * 1024);
    }

    const char* rd = sm + lane * 16;

    for (int t = 0; t < 32; ++t) {
        const int kv0 = t * 64;
        const int slot = t % 3;

        VM_WAIT4();    // own stage(t) loads done; stage(t+1) still in flight
        BARRIER();     // all waves' stage(t) landed; all t-1 readers passed

        // issue stage(t+2) into slot (t+2)%3  (clamped tail re-stages tile 31)
        {
            int tn = (t + 2 < 32) ? t + 2 : 31;
            char* Kb = sm + ((t + 2) % 3) * 16384, *Vb = Kb + 8192;
            const char* kc = KtB + (size_t)tn * 8192 + lane * 16;
            const char* vc = VtB + (size_t)tn * 8192 + lane * 16;
            GLOAD16(kc + c0 * 1024, Kb + c0 * 1024);
            GLOAD16(kc + c1 * 1024, Kb + c1 * 1024);
            GLOAD16(vc + c0 * 1024, Vb + c0 * 1024);
            GLOAD16(vc + c1 * 1024, Vb + c1 * 1024);
        }

        const char* Kr = rd + slot * 16384;
        const char* Vr = Kr + 8192;

        // mask tile from LDS: value + indicator (for 1-fma apply)
        float4 mk[2][4], mi[2][4];
#pragma unroll
        for (int cm = 0; cm < 2; ++cm)
#pragma unroll
            for (int rq = 0; rq < 4; ++rq) {
                float4 m4 = *(const float4*)(Msk + kv0 + cm * 32 + rq * 8 + g2 * 4);
                mk[cm][rq] = m4;
                mi[cm][rq].x = (m4.x >= 0.f) ? 1.f : 0.f;
                mi[cm][rq].y = (m4.y >= 0.f) ? 1.f : 0.f;
                mi[cm][rq].z = (m4.z >= 0.f) ? 1.f : 0.f;
                mi[cm][rq].w = (m4.w >= 0.f) ? 1.f : 0.f;
            }

        // S^T = K * Q^T
        f32x16 st[2][2];
#pragma unroll
        for (int cm = 0; cm < 2; ++cm)
#pragma unroll
            for (int qn = 0; qn < 2; ++qn)
#pragma unroll
                for (int r = 0; r < 16; ++r) st[cm][qn][r] = 0.f;
#pragma unroll
        for (int ks = 0; ks < 4; ++ks) {
#pragma unroll
            for (int cm = 0; cm < 2; ++cm) {
                short8 kf = *(const short8*)(Kr + (cm * 4 + ks) * 1024);
#pragma unroll
                for (int qn = 0; qn < 2; ++qn)
                    st[cm][qn] = __builtin_amdgcn_mfma_f32_32x32x16_bf16(
                        kf, qf[qn][ks], st[cm][qn], 0, 0, 0);
            }
        }

        // V^T fragments (shared by both qn)
        short8 vf[2][4];
#pragma unroll
        for (int dm = 0; dm < 2; ++dm)
#pragma unroll
            for (int ks = 0; ks < 4; ++ks)
                vf[dm][ks] = *(const short8*)(Vr + (dm * 4 + ks) * 1024);

#pragma unroll
        for (int qn = 0; qn < 2; ++qn) {
            // mask apply (1 fma) + row max
            float tm = -3e38f;
#pragma unroll
            for (int cm = 0; cm < 2; ++cm)
#pragma unroll
                for (int rq = 0; rq < 4; ++rq)
#pragma unroll
                    for (int j = 0; j < 4; ++j) {
                        float sv = fmaf(st[cm][qn][rq * 4 + j],
                                        f4get(mi[cm][rq], j), f4get(mk[cm][rq], j));
                        st[cm][qn][rq * 4 + j] = sv;
                        tm = fmaxf(tm, sv);
                    }
            tm = fmaxf(tm, __shfl_xor(tm, 32));

            // defer-max
            if (__any(tm > mN[qn] + 10.f)) {
                float mnew = fmaxf(mN[qn], tm);
                float ps;
                asm("v_exp_f32 %0, %1" : "=v"(ps) : "v"(mN[qn] - mnew));
                mN[qn] = mnew;
                lN[qn] *= ps;
#pragma unroll
                for (int dm = 0; dm < 2; ++dm)
#pragma unroll
                    for (int r = 0; r < 16; ++r) o[dm][qn][r] *= ps;
            }

            // P = 2^(S' - m), row sum
            float ts = 0.f;
#pragma unroll
            for (int cm = 0; cm < 2; ++cm)
#pragma unroll
                for (int r = 0; r < 16; ++r) {
                    float p;
                    asm("v_exp_f32 %0, %1" : "=v"(p) : "v"(st[cm][qn][r] - mN[qn]));
                    st[cm][qn][r] = p;
                    ts += p;
                }
            ts += __shfl_xor(ts, 32);
            lN[qn] += ts;

            // PV: O^T += V^T * P^T
#pragma unroll
            for (int ks = 0; ks < 4; ++ks) {
                const int cm = ks >> 1;
                const int b0 = 8 * (ks & 1);
                unsigned x0, x1, y0, y1;
                asm("v_cvt_pk_bf16_f32 %0, %1, %2" : "=v"(x0) : "v"(st[cm][qn][b0 + 0]), "v"(st[cm][qn][b0 + 1]));
                asm("v_cvt_pk_bf16_f32 %0, %1, %2" : "=v"(x1) : "v"(st[cm][qn][b0 + 2]), "v"(st[cm][qn][b0 + 3]));
                asm("v_cvt_pk_bf16_f32 %0, %1, %2" : "=v"(y0) : "v"(st[cm][qn][b0 + 4]), "v"(st[cm][qn][b0 + 5]));
                asm("v_cvt_pk_bf16_f32 %0, %1, %2" : "=v"(y1) : "v"(st[cm][qn][b0 + 6]), "v"(st[cm][qn][b0 + 7]));
                asm("v_permlane32_swap_b32 %0, %1" : "+v"(x0), "+v"(y0));
                asm("v_permlane32_swap_b32 %0, %1" : "+v"(x1), "+v"(y1));
                union { unsigned u[4]; short8 s; } pb;
                pb.u[0] = x0; pb.u[1] = x1; pb.u[2] = y0; pb.u[3] = y1;
#pragma unroll
                for (int dm = 0; dm < 2; ++dm)
                    o[dm][qn] = __builtin_amdgcn_mfma_f32_32x32x16_bf16(
                        vf[dm][ks], pb.s, o[dm][qn], 0, 0, 0);
            }
        }
    }

    // epilogue: divide by l, write fp32 [B,S,D]
#pragma unroll
    for (int qn = 0; qn < 2; ++qn) {
        float inv = 1.f / lN[qn];
        int q = q0w + qn * 32 + l31;
#pragma unroll
        for (int dm = 0; dm < 2; ++dm)
#pragma unroll
            for (int rq = 0; rq < 4; ++rq) {
                float4 v;
                v.x = o[dm][qn][rq * 4 + 0] * inv;
                v.y = o[dm][qn][rq * 4 + 1] * inv;
                v.z = o[dm][qn][rq * 4 + 2] * inv;
                v.w = o[dm][qn][rq * 4 + 3] * inv;
                int d = dm * 32 + rq * 8 + g2 * 4;
                *(float4*)(out + (size_t)(bb * 2048 + q) * 1024 + h * 64 + d) = v;
            }
    }
}

extern "C" void kernel_launch(void* const* d_in, const int* in_sizes, int n_in,
                              void* d_out, int out_size, void* d_ws, size_t ws_size,
                              hipStream_t stream) {
    const float* X    = (const float*)d_in[0];
    const float* mask = (const float*)d_in[1];
    const float* Wq   = (const float*)d_in[2];
    const float* bq   = (const float*)d_in[3];
    const float* Wk   = (const float*)d_in[4];
    const float* bk   = (const float*)d_in[5];
    const float* Wv   = (const float*)d_in[6];
    const float* bv   = (const float*)d_in[7];
    float* out = (float*)d_out;

    char* ws = (char*)d_ws;
    unsigned short* Xb = (unsigned short*)(ws + OFF_XB);
    unsigned short* Wc = (unsigned short*)(ws + OFF_WC);
    float*          M2 = (float*)(ws + OFF_M2);
    unsigned short* Qb = (unsigned short*)(ws + OFF_QB);
    char*           Kt = ws + OFF_KT;
    char*           Vt = ws + OFF_VT;

    convert_kernel<<<11272, 256, 0, stream>>>(X, Wq, Wk, Wv, mask, Xb, Wc, M2);
    qkv_gemm<<<dim3(64, 24), 256, 0, stream>>>(Xb, Wc, bq, bk, bv, Qb, Kt, Vt);
    attn_kernel<<<512, 256, 0, stream>>>(Qb, Kt, Vt, M2, out);
}

// Round 6
// 216.757 us; speedup vs baseline: 1.0419x; 1.0419x over previous
//
#include <hip/hip_runtime.h>

typedef __attribute__((ext_vector_type(8)))  short short8;
typedef __attribute__((ext_vector_type(4)))  float f32x4;
typedef __attribute__((ext_vector_type(16))) float f32x16;

#define Bv 4
#define Sv 2048
#define Dv 1024
#define Hv 16
#define HDv 64

// workspace byte offsets
#define OFF_XB  (size_t)0           // X bf16      [8192][1024]  16MB
#define OFF_WC  (size_t)16777216    // Wcat bf16   [3072][1024]   6MB
#define OFF_M2  (size_t)23068672    // mask*log2e  [4][2048]     32KB
#define OFF_QT  (size_t)25165824    // Q tiled [64][32][8][1KB]  16MB (scaled 0.125*log2e)
#define OFF_KT  (size_t)41943040    // K tiled [64][32][8][1KB]  16MB
#define OFF_VT  (size_t)58720256    // V tiled [64][32][8][1KB]  16MB

#define QSCALE 0.180336879f   /* 0.125 * log2(e) */
#define LOG2E  1.44269504f

__device__ __forceinline__ unsigned short f2bf(float f) {
    union { float f; unsigned u; } v; v.f = f;
    unsigned r = v.u + 0x7FFFu + ((v.u >> 16) & 1u);   // RNE
    return (unsigned short)(r >> 16);
}
__device__ __forceinline__ float f4get(const float4& v, int i) {
    return i == 0 ? v.x : i == 1 ? v.y : i == 2 ? v.z : v.w;
}

#define GLOAD16(gp, lp)                                                        \
    __builtin_amdgcn_global_load_lds(                                          \
        (const __attribute__((address_space(1))) void*)(gp),                   \
        (__attribute__((address_space(3))) void*)(lp), 16, 0, 0)

// ---------------------------------------------------------------------------
// fp32 -> bf16 convert: X, Wq|Wk|Wv -> Wcat; mask -> mask*log2e (fp32)
// ---------------------------------------------------------------------------
__global__ void convert_kernel(const float* __restrict__ X,
                               const float* __restrict__ Wq,
                               const float* __restrict__ Wk,
                               const float* __restrict__ Wv,
                               const float* __restrict__ mask,
                               unsigned short* __restrict__ Xb,
                               unsigned short* __restrict__ Wc,
                               float* __restrict__ M2) {
    size_t i = ((size_t)blockIdx.x * 256 + threadIdx.x) * 4;
    if (i < 8388608) {
        float4 v = *(const float4*)(X + i);
        ushort4 o; o.x = f2bf(v.x); o.y = f2bf(v.y); o.z = f2bf(v.z); o.w = f2bf(v.w);
        *(ushort4*)(Xb + i) = o;
    } else if (i < 11534336) {
        size_t j = i - 8388608;
        int which = (int)(j >> 20);
        size_t r = j & 1048575;
        const float* W = which == 0 ? Wq : which == 1 ? Wk : Wv;
        float4 v = *(const float4*)(W + r);
        ushort4 o; o.x = f2bf(v.x); o.y = f2bf(v.y); o.z = f2bf(v.z); o.w = f2bf(v.w);
        *(ushort4*)(Wc + j) = o;
    } else {
        size_t j = i - 11534336;   // 8192 mask floats
        float4 v = *(const float4*)(mask + j);
        v.x *= LOG2E; v.y *= LOG2E; v.z *= LOG2E; v.w *= LOG2E;
        *(float4*)(M2 + j) = v;
    }
}

// ---------------------------------------------------------------------------
// QKV projection GEMM: [8192 x 1024] x [3072 x 1024]^T + bias -> bf16.
// Fragment-linear LDS staging, XCD-swizzled grid.  Epilogue: acc scattered
// into LDS in the attention kernel's tiled layout [bh][tile][chunk8][1KB],
// then copied out as coalesced 1KB-per-wave bursts.
//   Q/K chunk = ((s>>5)&1)*4 + (d>>4); byte = (s&31)*16 + ((d>>3)&1)*512 + (d&7)*2
//   V   chunk = (d>>5)*4 + ((s>>4)&3); byte = (d&31)*16 + ((s>>3)&1)*512 + (s&7)*2
// ---------------------------------------------------------------------------
__global__ void qkv_gemm(const unsigned short* __restrict__ Xb,
                         const unsigned short* __restrict__ Wc,
                         const float* __restrict__ bq,
                         const float* __restrict__ bk,
                         const float* __restrict__ bv,
                         char* __restrict__ Qt,
                         char* __restrict__ Kt,
                         char* __restrict__ Vt) {
    __shared__ __align__(16) char sm[32768];
    char* As = sm;
    char* Bs = sm + 16384;

    const int tid  = threadIdx.x;
    const int w    = tid >> 6, lane = tid & 63;
    const int l15  = lane & 15, g = lane >> 4;

    const int lin  = blockIdx.x + (blockIdx.y << 6);
    const int lin2 = (lin & 7) * 192 + (lin >> 3);
    const int m0   = (lin2 / 24) * 128;
    const int n0   = (lin2 % 24) * 128;

    const int wr   = (w >> 1) * 64, wc = (w & 1) * 64;

    const size_t laneoff = (size_t)l15 * 2048 + g * 16;
    const char* gA0 = (const char*)Xb + ((size_t)m0 + 2 * w * 16) * 2048 + laneoff;
    const char* gB0 = (const char*)Wc + ((size_t)n0 + 2 * w * 16) * 2048 + laneoff;
    char* lA = As + (2 * w) * 2048;
    char* lB = Bs + (2 * w) * 2048;

    f32x4 acc[4][4];
#pragma unroll
    for (int a = 0; a < 4; ++a)
#pragma unroll
        for (int b = 0; b < 4; ++b)
#pragma unroll
            for (int r = 0; r < 4; ++r) acc[a][b][r] = 0.f;

    const int rbA = (w >> 1) * 4;
    const int rbB = (w & 1) * 4;

    for (int k0 = 0; k0 < 1024; k0 += 64) {
        __syncthreads();
#pragma unroll
        for (int i = 0; i < 2; ++i) {
#pragma unroll
            for (int ks = 0; ks < 2; ++ks) {
                GLOAD16(gA0 + i * 32768 + ks * 64 + k0 * 2, lA + i * 2048 + ks * 1024);
                GLOAD16(gB0 + i * 32768 + ks * 64 + k0 * 2, lB + i * 2048 + ks * 1024);
            }
        }
        __syncthreads();
#pragma unroll
        for (int ks = 0; ks < 2; ++ks) {
            short8 af[4], bf[4];
#pragma unroll
            for (int fm = 0; fm < 4; ++fm)
                af[fm] = *(const short8*)(As + ((rbA + fm) * 2 + ks) * 1024 + lane * 16);
#pragma unroll
            for (int fn = 0; fn < 4; ++fn)
                bf[fn] = *(const short8*)(Bs + ((rbB + fn) * 2 + ks) * 1024 + lane * 16);
#pragma unroll
            for (int fm = 0; fm < 4; ++fm)
#pragma unroll
                for (int fn = 0; fn < 4; ++fn)
                    acc[fm][fn] = __builtin_amdgcn_mfma_f32_16x16x32_bf16(
                        af[fm], bf[fn], acc[fm][fn], 0, 0, 0);
        }
    }

    // ---- epilogue: scatter into LDS in tiled layout, then coalesced copy ----
    const int which = n0 >> 10;
    const float* bias = which == 0 ? bq : which == 1 ? bk : bv;
    const float osc = (which == 0) ? QSCALE : 1.0f;
    const int h2 = w & 1;              // head half this wave owns (wc>>6)

    __syncthreads();   // protect last K-step's As/Bs reads before reuse

    if (which <= 1) {  // Q/K layout
#pragma unroll
        for (int fn = 0; fn < 4; ++fn) {
            int nn = (n0 & 1023) + wc + fn * 16 + l15;
            float bvv = bias[nn];
            int dd = fn * 16 + l15;
            int dpart = ((dd >> 3) & 1) * 512 + (dd & 7) * 2 + ((dd >> 4) << 10);
#pragma unroll
            for (int fm = 0; fm < 4; ++fm) {
                int sl0 = wr + fm * 16 + 4 * g;          // 0..127
                int kvt = sl0 >> 6, sb = sl0 & 63;
                char* base = sm + ((h2 * 2 + kvt) << 13) + (((sb >> 5) & 1) << 12)
                             + dpart;
#pragma unroll
                for (int r = 0; r < 4; ++r)
                    *(unsigned short*)(base + ((sb + r) & 31) * 16) =
                        f2bf((acc[fm][fn][r] + bvv) * osc);
            }
        }
    } else {           // V layout
#pragma unroll
        for (int fn = 0; fn < 4; ++fn) {
            int nn = (n0 & 1023) + wc + fn * 16 + l15;
            float bvv = bias[nn];
            int dd = fn * 16 + l15;
#pragma unroll
            for (int fm = 0; fm < 4; ++fm) {
                int sl0 = wr + fm * 16 + 4 * g;
                int kvt = sl0 >> 6, sb = sl0 & 63;
                char* pos = sm + ((h2 * 2 + kvt) << 13)
                            + (((dd >> 5) * 4 + ((sb >> 4) & 3)) << 10)
                            + (dd & 31) * 16 + ((sb >> 3) & 1) * 512 + (sb & 7) * 2;
                ushort4 pk;
                pk.x = f2bf(acc[fm][fn][0] + bvv);
                pk.y = f2bf(acc[fm][fn][1] + bvv);
                pk.z = f2bf(acc[fm][fn][2] + bvv);
                pk.w = f2bf(acc[fm][fn][3] + bvv);
                *(ushort4*)(pos) = pk;
            }
        }
    }
    __syncthreads();

    // cooperative coalesced copy: region tid>>6, 8 x 16B per thread
    {
        char* OutT = which == 0 ? Qt : which == 1 ? Kt : Vt;
        int rgn = w;                       // 4 regions of 8KB
        int h_ = rgn >> 1, kvt_ = rgn & 1;
        int b = m0 >> 11, st0 = (m0 & 2047) >> 6;
        int h0 = (n0 & 1023) >> 6;
        char* dst = OutT + ((size_t)(b * 16 + h0 + h_) * 32 + st0 + kvt_) * 8192;
        const char* src = sm + rgn * 8192;
#pragma unroll
        for (int j = 0; j < 8; ++j)
            *(int4*)(dst + j * 1024 + lane * 16) = *(const int4*)(src + j * 1024 + lane * 16);
    }
}

// ---------------------------------------------------------------------------
// Flash attention: 4 waves x 32 q-rows = 128-row q-tile, kv tiles of 64,
// double-buffered fragment-linear LDS (1KB staging bursts), swapped S^T/O^T
// MFMA, exp2 softmax, cvt_pk+permlane packing, defer-max.
// 1024 blocks -> 4 blocks/CU, 16 waves/CU.
// ---------------------------------------------------------------------------
__global__ __launch_bounds__(256, 4) void attn_kernel(
    const char* __restrict__ Qt,
    const char* __restrict__ Kt,
    const char* __restrict__ Vt,
    const float* __restrict__ M2,
    float* __restrict__ out) {
    __shared__ __align__(16) char sm[32768];   // 2 x (K 8KB | V 8KB)
    const int tid = threadIdx.x;
    const int w = tid >> 6, lane = tid & 63;
    const int l31 = lane & 31, g2 = lane >> 5;
    const int lin = blockIdx.x;
    const int bh = lin & 63, qt = lin >> 6;     // qt 0..15
    const int bb = bh >> 4, h = bh & 15;
    const int qrow = qt * 128 + w * 32 + l31;
    const float* mrow = M2 + bb * 2048;

    const char* QtB = Qt + (size_t)bh * 262144;
    const char* KtB = Kt + (size_t)bh * 262144;
    const char* VtB = Vt + (size_t)bh * 262144;

    // wave stages 4 chunks: w<2 -> K chunks 4w..4w+3; w>=2 -> V chunks
    const int cbase = w * 4;

    // Q fragments from tiled layout (chunk = qn'*4+ks, qn' = w&1)
    const int qtile = qt * 2 + (w >> 1);
    short8 qf[4];
#pragma unroll
    for (int ks = 0; ks < 4; ++ks)
        qf[ks] = *(const short8*)(QtB + qtile * 8192 + ((w & 1) * 4 + ks) * 1024
                                  + l31 * 16 + g2 * 512);

    f32x16 o[2];
#pragma unroll
    for (int dm = 0; dm < 2; ++dm)
#pragma unroll
        for (int r = 0; r < 16; ++r) o[dm][r] = 0.f;
    float mN = -3e38f, lN = 0.f;

    // prologue: stage tile 0 into buf 0
    {
        char* db = sm;
#pragma unroll
        for (int i = 0; i < 4; ++i) {
            int c = cbase + i;
            const char* src = (c < 8 ? KtB + c * 1024 : VtB + (c - 8) * 1024) + lane * 16;
            GLOAD16(src, db + c * 1024);
        }
    }
    __syncthreads();

    const char* rd = sm + lane * 16;

    for (int t = 0; t < 32; ++t) {
        const int kv0 = t * 64;
        const int buf = t & 1;

        if (t + 1 < 32) {   // stage next tile into buf^1
            char* db = sm + (buf ^ 1) * 16384;
            const char* kb = KtB + (size_t)(t + 1) * 8192;
            const char* vb = VtB + (size_t)(t + 1) * 8192;
#pragma unroll
            for (int i = 0; i < 4; ++i) {
                int c = cbase + i;
                const char* src = (c < 8 ? kb + c * 1024 : vb + (c - 8) * 1024) + lane * 16;
                GLOAD16(src, db + c * 1024);
            }
        }

        const char* Kr = rd + buf * 16384;
        const char* Vr = Kr + 8192;

        // S^T = K * Q^T
        f32x16 st[2];
#pragma unroll
        for (int cm = 0; cm < 2; ++cm)
#pragma unroll
            for (int r = 0; r < 16; ++r) st[cm][r] = 0.f;
#pragma unroll
        for (int ks = 0; ks < 4; ++ks)
#pragma unroll
            for (int cm = 0; cm < 2; ++cm) {
                short8 kf = *(const short8*)(Kr + (cm * 4 + ks) * 1024);
                st[cm] = __builtin_amdgcn_mfma_f32_32x32x16_bf16(
                    kf, qf[ks], st[cm], 0, 0, 0);
            }

        // mask apply (indicator fma) + row max
        float tm = -3e38f;
#pragma unroll
        for (int cm = 0; cm < 2; ++cm)
#pragma unroll
            for (int rq = 0; rq < 4; ++rq) {
                float4 mk4 = *(const float4*)(mrow + kv0 + cm * 32 + rq * 8 + g2 * 4);
#pragma unroll
                for (int j = 0; j < 4; ++j) {
                    float mk = f4get(mk4, j);
                    float ind = (mk >= 0.f) ? 1.f : 0.f;
                    float sv = fmaf(st[cm][rq * 4 + j], ind, mk);
                    st[cm][rq * 4 + j] = sv;
                    tm = fmaxf(tm, sv);
                }
            }
        tm = fmaxf(tm, __shfl_xor(tm, 32));

        // defer-max
        if (__any(tm > mN + 10.f)) {
            float mnew = fmaxf(mN, tm);
            float ps;
            asm("v_exp_f32 %0, %1" : "=v"(ps) : "v"(mN - mnew));
            mN = mnew;
            lN *= ps;
#pragma unroll
            for (int dm = 0; dm < 2; ++dm)
#pragma unroll
                for (int r = 0; r < 16; ++r) o[dm][r] *= ps;
        }

        // P = 2^(S' - m), row sum
        float ts = 0.f;
#pragma unroll
        for (int cm = 0; cm < 2; ++cm)
#pragma unroll
            for (int r = 0; r < 16; ++r) {
                float p;
                asm("v_exp_f32 %0, %1" : "=v"(p) : "v"(st[cm][r] - mN));
                st[cm][r] = p;
                ts += p;
            }
        ts += __shfl_xor(ts, 32);
        lN += ts;

        // PV: O^T += V^T * P^T
#pragma unroll
        for (int ks = 0; ks < 4; ++ks) {
            const int cm = ks >> 1;
            const int b0 = 8 * (ks & 1);
            unsigned x0, x1, y0, y1;
            asm("v_cvt_pk_bf16_f32 %0, %1, %2" : "=v"(x0) : "v"(st[cm][b0 + 0]), "v"(st[cm][b0 + 1]));
            asm("v_cvt_pk_bf16_f32 %0, %1, %2" : "=v"(x1) : "v"(st[cm][b0 + 2]), "v"(st[cm][b0 + 3]));
            asm("v_cvt_pk_bf16_f32 %0, %1, %2" : "=v"(y0) : "v"(st[cm][b0 + 4]), "v"(st[cm][b0 + 5]));
            asm("v_cvt_pk_bf16_f32 %0, %1, %2" : "=v"(y1) : "v"(st[cm][b0 + 6]), "v"(st[cm][b0 + 7]));
            asm("v_permlane32_swap_b32 %0, %1" : "+v"(x0), "+v"(y0));
            asm("v_permlane32_swap_b32 %0, %1" : "+v"(x1), "+v"(y1));
            union { unsigned u[4]; short8 s; } pb;
            pb.u[0] = x0; pb.u[1] = x1; pb.u[2] = y0; pb.u[3] = y1;
#pragma unroll
            for (int dm = 0; dm < 2; ++dm) {
                short8 vf = *(const short8*)(Vr + (dm * 4 + ks) * 1024);
                o[dm] = __builtin_amdgcn_mfma_f32_32x32x16_bf16(
                    vf, pb.s, o[dm], 0, 0, 0);
            }
        }
        __syncthreads();   // next tile staged + this tile's LDS reads done
    }

    // epilogue: divide by l, write fp32 [B,S,D]
    float inv = 1.f / lN;
#pragma unroll
    for (int dm = 0; dm < 2; ++dm)
#pragma unroll
        for (int rq = 0; rq < 4; ++rq) {
            float4 v;
            v.x = o[dm][rq * 4 + 0] * inv;
            v.y = o[dm][rq * 4 + 1] * inv;
            v.z = o[dm][rq * 4 + 2] * inv;
            v.w = o[dm][rq * 4 + 3] * inv;
            int d = dm * 32 + rq * 8 + g2 * 4;
            *(float4*)(out + (size_t)(bb * 2048 + qrow) * 1024 + h * 64 + d) = v;
        }
}

extern "C" void kernel_launch(void* const* d_in, const int* in_sizes, int n_in,
                              void* d_out, int out_size, void* d_ws, size_t ws_size,
                              hipStream_t stream) {
    const float* X    = (const float*)d_in[0];
    const float* mask = (const float*)d_in[1];
    const float* Wq   = (const float*)d_in[2];
    const float* bq   = (const float*)d_in[3];
    const float* Wk   = (const float*)d_in[4];
    const float* bk   = (const float*)d_in[5];
    const float* Wv   = (const float*)d_in[6];
    const float* bv   = (const float*)d_in[7];
    float* out = (float*)d_out;

    char* ws = (char*)d_ws;
    unsigned short* Xb = (unsigned short*)(ws + OFF_XB);
    unsigned short* Wc = (unsigned short*)(ws + OFF_WC);
    float*          M2 = (float*)(ws + OFF_M2);
    char*           Qt = ws + OFF_QT;
    char*           Kt = ws + OFF_KT;
    char*           Vt = ws + OFF_VT;

    convert_kernel<<<11272, 256, 0, stream>>>(X, Wq, Wk, Wv, mask, Xb, Wc, M2);
    qkv_gemm<<<dim3(64, 24), 256, 0, stream>>>(Xb, Wc, bq, bk, bv, Qt, Kt, Vt);
    attn_kernel<<<1024, 256, 0, stream>>>(Qt, Kt, Vt, M2, out);
}

// Round 9
// 206.443 us; speedup vs baseline: 1.0940x; 1.0500x over previous
//
#include <hip/hip_runtime.h>

typedef __attribute__((ext_vector_type(8)))  short short8;
typedef __attribute__((ext_vector_type(4)))  float f32x4;
typedef __attribute__((ext_vector_type(16))) float f32x16;

#define Bv 4
#define Sv 2048
#define Dv 1024
#define Hv 16
#define HDv 64

// workspace byte offsets
#define OFF_XB  (size_t)0           // X bf16      [8192][1024]  16MB
#define OFF_WC  (size_t)16777216    // Wcat bf16   [3072][1024]   6MB
#define OFF_M2  (size_t)23068672    // mask*log2e  [4][2048]     32KB
#define OFF_QT  (size_t)25165824    // Q tiled [64][32][8][1KB]  16MB (scaled 0.125*log2e)
#define OFF_KT  (size_t)41943040    // K tiled [64][32][8][1KB]  16MB (masked rows zeroed)
#define OFF_VT  (size_t)58720256    // V tiled [64][32][8][1KB]  16MB

#define QSCALE 0.180336879f   /* 0.125 * log2(e) */
#define LOG2E  1.44269504f

__device__ __forceinline__ unsigned short f2bf(float f) {
    union { float f; unsigned u; } v; v.f = f;
    unsigned r = v.u + 0x7FFFu + ((v.u >> 16) & 1u);   // RNE
    return (unsigned short)(r >> 16);
}
__device__ __forceinline__ float f4get(const float4& v, int i) {
    return i == 0 ? v.x : i == 1 ? v.y : i == 2 ? v.z : v.w;
}

#define GLOAD16(gp, lp)                                                        \
    __builtin_amdgcn_global_load_lds(                                          \
        (const __attribute__((address_space(1))) void*)(gp),                   \
        (__attribute__((address_space(3))) void*)(lp), 16, 0, 0)

// ---------------------------------------------------------------------------
// fp32 -> bf16 convert: X, Wq|Wk|Wv -> Wcat; mask -> mask*log2e (fp32)
// ---------------------------------------------------------------------------
__global__ void convert_kernel(const float* __restrict__ X,
                               const float* __restrict__ Wq,
                               const float* __restrict__ Wk,
                               const float* __restrict__ Wv,
                               const float* __restrict__ mask,
                               unsigned short* __restrict__ Xb,
                               unsigned short* __restrict__ Wc,
                               float* __restrict__ M2) {
    size_t i = ((size_t)blockIdx.x * 256 + threadIdx.x) * 4;
    if (i < 8388608) {
        float4 v = *(const float4*)(X + i);
        ushort4 o; o.x = f2bf(v.x); o.y = f2bf(v.y); o.z = f2bf(v.z); o.w = f2bf(v.w);
        *(ushort4*)(Xb + i) = o;
    } else if (i < 11534336) {
        size_t j = i - 8388608;
        int which = (int)(j >> 20);
        size_t r = j & 1048575;
        const float* W = which == 0 ? Wq : which == 1 ? Wk : Wv;
        float4 v = *(const float4*)(W + r);
        ushort4 o; o.x = f2bf(v.x); o.y = f2bf(v.y); o.z = f2bf(v.z); o.w = f2bf(v.w);
        *(ushort4*)(Wc + j) = o;
    } else {
        size_t j = i - 11534336;   // 8192 mask floats
        float4 v = *(const float4*)(mask + j);
        v.x *= LOG2E; v.y *= LOG2E; v.z *= LOG2E; v.w *= LOG2E;
        *(float4*)(M2 + j) = v;
    }
}

// ---------------------------------------------------------------------------
// QKV projection GEMM: [8192 x 1024] x [3072 x 1024]^T + bias -> bf16.
// Fragment-linear LDS staging, XCD-swizzled grid.  Epilogue: acc scattered
// into LDS in the attention kernel's tiled layout, coalesced copy out.
// Q scaled by 0.125*log2e; K rows with mask<0 are ZEROED (indicator baked in).
// ---------------------------------------------------------------------------
__global__ void qkv_gemm(const unsigned short* __restrict__ Xb,
                         const unsigned short* __restrict__ Wc,
                         const float* __restrict__ bq,
                         const float* __restrict__ bk,
                         const float* __restrict__ bv,
                         const float* __restrict__ M2,
                         char* __restrict__ Qt,
                         char* __restrict__ Kt,
                         char* __restrict__ Vt) {
    __shared__ __align__(16) char sm[32768];
    char* As = sm;
    char* Bs = sm + 16384;

    const int tid  = threadIdx.x;
    const int w    = tid >> 6, lane = tid & 63;
    const int l15  = lane & 15, g = lane >> 4;

    const int lin  = blockIdx.x + (blockIdx.y << 6);
    const int lin2 = (lin & 7) * 192 + (lin >> 3);
    const int m0   = (lin2 / 24) * 128;
    const int n0   = (lin2 % 24) * 128;

    const int wr   = (w >> 1) * 64, wc = (w & 1) * 64;

    const size_t laneoff = (size_t)l15 * 2048 + g * 16;
    const char* gA0 = (const char*)Xb + ((size_t)m0 + 2 * w * 16) * 2048 + laneoff;
    const char* gB0 = (const char*)Wc + ((size_t)n0 + 2 * w * 16) * 2048 + laneoff;
    char* lA = As + (2 * w) * 2048;
    char* lB = Bs + (2 * w) * 2048;

    f32x4 acc[4][4];
#pragma unroll
    for (int a = 0; a < 4; ++a)
#pragma unroll
        for (int b = 0; b < 4; ++b)
#pragma unroll
            for (int r = 0; r < 4; ++r) acc[a][b][r] = 0.f;

    const int rbA = (w >> 1) * 4;
    const int rbB = (w & 1) * 4;

    for (int k0 = 0; k0 < 1024; k0 += 64) {
        __syncthreads();
#pragma unroll
        for (int i = 0; i < 2; ++i) {
#pragma unroll
            for (int ks = 0; ks < 2; ++ks) {
                GLOAD16(gA0 + i * 32768 + ks * 64 + k0 * 2, lA + i * 2048 + ks * 1024);
                GLOAD16(gB0 + i * 32768 + ks * 64 + k0 * 2, lB + i * 2048 + ks * 1024);
            }
        }
        __syncthreads();
#pragma unroll
        for (int ks = 0; ks < 2; ++ks) {
            short8 af[4], bf[4];
#pragma unroll
            for (int fm = 0; fm < 4; ++fm)
                af[fm] = *(const short8*)(As + ((rbA + fm) * 2 + ks) * 1024 + lane * 16);
#pragma unroll
            for (int fn = 0; fn < 4; ++fn)
                bf[fn] = *(const short8*)(Bs + ((rbB + fn) * 2 + ks) * 1024 + lane * 16);
#pragma unroll
            for (int fm = 0; fm < 4; ++fm)
#pragma unroll
                for (int fn = 0; fn < 4; ++fn)
                    acc[fm][fn] = __builtin_amdgcn_mfma_f32_16x16x32_bf16(
                        af[fm], bf[fn], acc[fm][fn], 0, 0, 0);
        }
    }

    // ---- epilogue: scatter into LDS in tiled layout, then coalesced copy ----
    const int which = n0 >> 10;
    const float* bias = which == 0 ? bq : which == 1 ? bk : bv;
    const float osc = (which == 0) ? QSCALE : 1.0f;
    const int h2 = w & 1;

    // K: per-row indicator from mask sign (batch b = m0>>11, s = m0&2047 + sl0)
    float4 msc[4];
    if (which == 1) {
#pragma unroll
        for (int fm = 0; fm < 4; ++fm) {
            int sl0 = wr + fm * 16 + 4 * g;
            float4 mv = *(const float4*)(M2 + (m0 >> 11) * 2048 + (m0 & 2047) + sl0);
            msc[fm].x = (mv.x >= 0.f) ? 1.f : 0.f;
            msc[fm].y = (mv.y >= 0.f) ? 1.f : 0.f;
            msc[fm].z = (mv.z >= 0.f) ? 1.f : 0.f;
            msc[fm].w = (mv.w >= 0.f) ? 1.f : 0.f;
        }
    }

    __syncthreads();   // protect last K-step's As/Bs reads before reuse

    if (which <= 1) {  // Q/K layout
#pragma unroll
        for (int fn = 0; fn < 4; ++fn) {
            int nn = (n0 & 1023) + wc + fn * 16 + l15;
            float bvv = bias[nn];
            int dd = fn * 16 + l15;
            int dpart = ((dd >> 3) & 1) * 512 + (dd & 7) * 2 + ((dd >> 4) << 10);
#pragma unroll
            for (int fm = 0; fm < 4; ++fm) {
                int sl0 = wr + fm * 16 + 4 * g;
                int kvt = sl0 >> 6, sb = sl0 & 63;
                char* base = sm + ((h2 * 2 + kvt) << 13) + (((sb >> 5) & 1) << 12)
                             + dpart;
#pragma unroll
                for (int r = 0; r < 4; ++r) {
                    float val = (acc[fm][fn][r] + bvv) * osc;
                    if (which == 1) val *= f4get(msc[fm], r);
                    *(unsigned short*)(base + ((sb + r) & 31) * 16) = f2bf(val);
                }
            }
        }
    } else {           // V layout
#pragma unroll
        for (int fn = 0; fn < 4; ++fn) {
            int nn = (n0 & 1023) + wc + fn * 16 + l15;
            float bvv = bias[nn];
            int dd = fn * 16 + l15;
#pragma unroll
            for (int fm = 0; fm < 4; ++fm) {
                int sl0 = wr + fm * 16 + 4 * g;
                int kvt = sl0 >> 6, sb = sl0 & 63;
                char* pos = sm + ((h2 * 2 + kvt) << 13)
                            + (((dd >> 5) * 4 + ((sb >> 4) & 3)) << 10)
                            + (dd & 31) * 16 + ((sb >> 3) & 1) * 512 + (sb & 7) * 2;
                ushort4 pk;
                pk.x = f2bf(acc[fm][fn][0] + bvv);
                pk.y = f2bf(acc[fm][fn][1] + bvv);
                pk.z = f2bf(acc[fm][fn][2] + bvv);
                pk.w = f2bf(acc[fm][fn][3] + bvv);
                *(ushort4*)(pos) = pk;
            }
        }
    }
    __syncthreads();

    // cooperative coalesced copy: region tid>>6, 8 x 16B per thread
    {
        char* OutT = which == 0 ? Qt : which == 1 ? Kt : Vt;
        int rgn = w;
        int h_ = rgn >> 1, kvt_ = rgn & 1;
        int b = m0 >> 11, st0 = (m0 & 2047) >> 6;
        int h0 = (n0 & 1023) >> 6;
        char* dst = OutT + ((size_t)(b * 16 + h0 + h_) * 32 + st0 + kvt_) * 8192;
        const char* src = sm + rgn * 8192;
#pragma unroll
        for (int j = 0; j < 8; ++j)
            *(int4*)(dst + j * 1024 + lane * 16) = *(const int4*)(src + j * 1024 + lane * 16);
    }
}

// ---------------------------------------------------------------------------
// Flash attention: 4 waves x 32 q-rows = 128-row q-tile, kv tiles of 64,
// double-buffered fragment-linear LDS, swapped S^T/O^T MFMA.
// Mask indicator baked into K (gemm); mask additive term is the MFMA C-init
// (layout identical to r6's verified post-MFMA apply).  Tree max/sum in-lane;
// cross-half combine via r6-verified __shfl_xor(.,32).  r6 defer-max.
// ---------------------------------------------------------------------------
__global__ __launch_bounds__(256, 4) void attn_kernel(
    const char* __restrict__ Qt,
    const char* __restrict__ Kt,
    const char* __restrict__ Vt,
    const float* __restrict__ M2,
    float* __restrict__ out) {
    __shared__ __align__(16) char sm[32768];   // 2 x (K 8KB | V 8KB)
    const int tid = threadIdx.x;
    const int w = tid >> 6, lane = tid & 63;
    const int l31 = lane & 31, g2 = lane >> 5;
    const int lin = blockIdx.x;
    const int bh = lin & 63, qt = lin >> 6;
    const int bb = bh >> 4, h = bh & 15;
    const int qrow = qt * 128 + w * 32 + l31;
    const float* mrow = M2 + bb * 2048;

    const char* QtB = Qt + (size_t)bh * 262144;
    const char* KtB = Kt + (size_t)bh * 262144;
    const char* VtB = Vt + (size_t)bh * 262144;

    const int cbase = w * 4;

    const int qtile = qt * 2 + (w >> 1);
    short8 qf[4];
#pragma unroll
    for (int ks = 0; ks < 4; ++ks)
        qf[ks] = *(const short8*)(QtB + qtile * 8192 + ((w & 1) * 4 + ks) * 1024
                                  + l31 * 16 + g2 * 512);

    f32x16 o[2];
#pragma unroll
    for (int dm = 0; dm < 2; ++dm)
#pragma unroll
        for (int r = 0; r < 16; ++r) o[dm][r] = 0.f;
    float mN = -3e38f, lN = 0.f;

    // prologue: stage tile 0 into buf 0
    {
        char* db = sm;
#pragma unroll
        for (int i = 0; i < 4; ++i) {
            int c = cbase + i;
            const char* src = (c < 8 ? KtB + c * 1024 : VtB + (c - 8) * 1024) + lane * 16;
            GLOAD16(src, db + c * 1024);
        }
    }
    __syncthreads();

    const char* rd = sm + lane * 16;

    for (int t = 0; t < 32; ++t) {
        const int kv0 = t * 64;
        const int buf = t & 1;

        if (t + 1 < 32) {   // stage next tile into buf^1
            char* db = sm + (buf ^ 1) * 16384;
            const char* kb = KtB + (size_t)(t + 1) * 8192;
            const char* vb = VtB + (size_t)(t + 1) * 8192;
#pragma unroll
            for (int i = 0; i < 4; ++i) {
                int c = cbase + i;
                const char* src = (c < 8 ? kb + c * 1024 : vb + (c - 8) * 1024) + lane * 16;
                GLOAD16(src, db + c * 1024);
            }
        }

        const char* Kr = rd + buf * 16384;
        const char* Vr = Kr + 8192;

        // C-init: st = mask*log2e  (key = kv0 + cm*32 + (r&3)+8*(r>>2)+4*g2)
        f32x16 st[2];
#pragma unroll
        for (int cm = 0; cm < 2; ++cm)
#pragma unroll
            for (int rq = 0; rq < 4; ++rq) {
                float4 mk4 = *(const float4*)(mrow + kv0 + cm * 32 + rq * 8 + g2 * 4);
                st[cm][rq * 4 + 0] = mk4.x;
                st[cm][rq * 4 + 1] = mk4.y;
                st[cm][rq * 4 + 2] = mk4.z;
                st[cm][rq * 4 + 3] = mk4.w;
            }

        // S^T = K*Q^T + C   (masked K rows are zero -> score = mask exactly)
#pragma unroll
        for (int ks = 0; ks < 4; ++ks)
#pragma unroll
            for (int cm = 0; cm < 2; ++cm) {
                short8 kf = *(const short8*)(Kr + (cm * 4 + ks) * 1024);
                st[cm] = __builtin_amdgcn_mfma_f32_32x32x16_bf16(
                    kf, qf[ks], st[cm], 0, 0, 0);
            }

        // row max: in-lane tree + r6-verified cross-half shuffle
        float red[8];
#pragma unroll
        for (int j = 0; j < 8; ++j)
            red[j] = fmaxf(fmaxf(st[0][j], st[0][j + 8]),
                           fmaxf(st[1][j], st[1][j + 8]));
#pragma unroll
        for (int j = 0; j < 4; ++j) red[j] = fmaxf(red[j], red[j + 4]);
        float tm = fmaxf(fmaxf(red[0], red[1]), fmaxf(red[2], red[3]));
        tm = fmaxf(tm, __shfl_xor(tm, 32));

        // defer-max (r6 form): rescale only when running max grows materially
        if (__any(tm > mN + 10.f)) {
            float mnew = fmaxf(mN, tm);
            float ps;
            asm("v_exp_f32 %0, %1" : "=v"(ps) : "v"(mN - mnew));
            mN = mnew;
            lN *= ps;
#pragma unroll
            for (int dm = 0; dm < 2; ++dm)
#pragma unroll
                for (int r = 0; r < 16; ++r) o[dm][r] *= ps;
        }

        // P = 2^(st - mN); sum via in-lane tree + cross-half shuffle
#pragma unroll
        for (int cm = 0; cm < 2; ++cm)
#pragma unroll
            for (int r = 0; r < 16; ++r) {
                float p;
                asm("v_exp_f32 %0, %1" : "=v"(p) : "v"(st[cm][r] - mN));
                st[cm][r] = p;
            }
        float s8[8];
#pragma unroll
        for (int j = 0; j < 8; ++j)
            s8[j] = (st[0][j] + st[0][j + 8]) + (st[1][j] + st[1][j + 8]);
#pragma unroll
        for (int j = 0; j < 4; ++j) s8[j] += s8[j + 4];
        float ts = (s8[0] + s8[1]) + (s8[2] + s8[3]);
        ts += __shfl_xor(ts, 32);
        lN += ts;

        // PV: O^T += V^T * P^T  (cvt_pk + permlane32_swap packing, r6 form)
#pragma unroll
        for (int ks = 0; ks < 4; ++ks) {
            const int cm = ks >> 1;
            const int b0 = 8 * (ks & 1);
            unsigned x0, x1, y0, y1;
            asm("v_cvt_pk_bf16_f32 %0, %1, %2" : "=v"(x0) : "v"(st[cm][b0 + 0]), "v"(st[cm][b0 + 1]));
            asm("v_cvt_pk_bf16_f32 %0, %1, %2" : "=v"(x1) : "v"(st[cm][b0 + 2]), "v"(st[cm][b0 + 3]));
            asm("v_cvt_pk_bf16_f32 %0, %1, %2" : "=v"(y0) : "v"(st[cm][b0 + 4]), "v"(st[cm][b0 + 5]));
            asm("v_cvt_pk_bf16_f32 %0, %1, %2" : "=v"(y1) : "v"(st[cm][b0 + 6]), "v"(st[cm][b0 + 7]));
            asm("v_permlane32_swap_b32 %0, %1" : "+v"(x0), "+v"(y0));
            asm("v_permlane32_swap_b32 %0, %1" : "+v"(x1), "+v"(y1));
            union { unsigned u[4]; short8 s; } pb;
            pb.u[0] = x0; pb.u[1] = x1; pb.u[2] = y0; pb.u[3] = y1;
#pragma unroll
            for (int dm = 0; dm < 2; ++dm) {
                short8 vf = *(const short8*)(Vr + (dm * 4 + ks) * 1024);
                o[dm] = __builtin_amdgcn_mfma_f32_32x32x16_bf16(
                    vf, pb.s, o[dm], 0, 0, 0);
            }
        }
        __syncthreads();   // next tile staged + this tile's LDS reads done
    }

    // epilogue: divide by l, write fp32 [B,S,D]
    float inv = 1.f / lN;
#pragma unroll
    for (int dm = 0; dm < 2; ++dm)
#pragma unroll
        for (int rq = 0; rq < 4; ++rq) {
            float4 v;
            v.x = o[dm][rq * 4 + 0] * inv;
            v.y = o[dm][rq * 4 + 1] * inv;
            v.z = o[dm][rq * 4 + 2] * inv;
            v.w = o[dm][rq * 4 + 3] * inv;
            int d = dm * 32 + rq * 8 + g2 * 4;
            *(float4*)(out + (size_t)(bb * 2048 + qrow) * 1024 + h * 64 + d) = v;
        }
}

extern "C" void kernel_launch(void* const* d_in, const int* in_sizes, int n_in,
                              void* d_out, int out_size, void* d_ws, size_t ws_size,
                              hipStream_t stream) {
    const float* X    = (const float*)d_in[0];
    const float* mask = (const float*)d_in[1];
    const float* Wq   = (const float*)d_in[2];
    const float* bq   = (const float*)d_in[3];
    const float* Wk   = (const float*)d_in[4];
    const float* bk   = (const float*)d_in[5];
    const float* Wv   = (const float*)d_in[6];
    const float* bv   = (const float*)d_in[7];
    float* out = (float*)d_out;

    char* ws = (char*)d_ws;
    unsigned short* Xb = (unsigned short*)(ws + OFF_XB);
    unsigned short* Wc = (unsigned short*)(ws + OFF_WC);
    float*          M2 = (float*)(ws + OFF_M2);
    char*           Qt = ws + OFF_QT;
    char*           Kt = ws + OFF_KT;
    char*           Vt = ws + OFF_VT;

    convert_kernel<<<11272, 256, 0, stream>>>(X, Wq, Wk, Wv, mask, Xb, Wc, M2);
    qkv_gemm<<<dim3(64, 24), 256, 0, stream>>>(Xb, Wc, bq, bk, bv, M2, Qt, Kt, Vt);
    attn_kernel<<<1024, 256, 0, stream>>>(Qt, Kt, Vt, M2, out);
}